// Round 1
// baseline (1774.346 us; speedup 1.0000x reference)
//
#include <hip/hip_runtime.h>
#include <hip/hip_bf16.h>
#include <math.h>

typedef __bf16 bf16x8 __attribute__((ext_vector_type(8)));
typedef float f32x4 __attribute__((ext_vector_type(4)));

#define NPTS 8192
#define SGRP 512
#define KNBR 32
#define CCH 384
#define LDSP 392   // padded ushort row stride for [l][c] LDS tiles

static __device__ __forceinline__ unsigned short f2b(float f) {
  union { float f; unsigned u; } v; v.f = f;
  return (unsigned short)((v.u + 0x7fffu + ((v.u >> 16) & 1u)) >> 16);
}
static __device__ __forceinline__ float b2f(unsigned short u) {
  union { unsigned u; float f; } v; v.u = ((unsigned)u) << 16;
  return v.f;
}
static __device__ __forceinline__ unsigned pk2(float a, float b) {
  return (unsigned)f2b(a) | ((unsigned)f2b(b) << 16);
}

// ---------------- weight folding: bn(conv(x)) = (W*s)x + (b*s+bb) ----------------
__global__ void fold_w_bf16(const float* __restrict__ W, const float* __restrict__ b,
                            const float* __restrict__ g, const float* __restrict__ bb,
                            unsigned short* __restrict__ Wd, float* __restrict__ bd, int Cin) {
  int o = blockIdx.x;
  float sc = g[o] / sqrtf(1.0f + 1e-5f);
  for (int c = threadIdx.x; c < Cin; c += blockDim.x)
    Wd[o * Cin + c] = f2b(W[o * Cin + c] * sc);
  if (threadIdx.x == 0) bd[o] = b[o] * sc + bb[o];
}
__global__ void fold_w_f32(const float* __restrict__ W, const float* __restrict__ b,
                           const float* __restrict__ g, const float* __restrict__ bb,
                           float* __restrict__ Wd, float* __restrict__ bd, int Cin) {
  int o = blockIdx.x;
  float sc = g[o] / sqrtf(1.0f + 1e-5f);
  for (int c = threadIdx.x; c < Cin; c += blockDim.x)
    Wd[o * Cin + c] = W[o * Cin + c] * sc;
  if (threadIdx.x == 0) bd[o] = b[o] * sc + bb[o];
}

// ---------------- FPS: exact numpy-matching farthest point sampling ----------------
__global__ __launch_bounds__(1024) void fps_kernel(const float* __restrict__ xyz,
                                                   int* __restrict__ cIdx) {
  #pragma clang fp contract(off)
  __shared__ float xs[NPTS], ys[NPTS], zs[NPTS];
  __shared__ float rv[16];
  __shared__ int ri[16];
  __shared__ int curSh;
  const int b = blockIdx.x, tid = threadIdx.x;
  const float* xb = xyz + (size_t)b * NPTS * 3;
  for (int i = tid; i < NPTS; i += 1024) {
    xs[i] = xb[i * 3 + 0];
    ys[i] = xb[i * 3 + 1];
    zs[i] = xb[i * 3 + 2];
  }
  float dists[8];
  #pragma unroll
  for (int j = 0; j < 8; ++j) dists[j] = __builtin_inff();
  if (tid == 0) cIdx[b * SGRP] = 0;
  int cur = 0;
  __syncthreads();
  for (int step = 1; step < SGRP; ++step) {
    float cx = xs[cur], cy = ys[cur], cz = zs[cur];
    float bv = -1.0f; int bi = 0x7fffffff;
    #pragma unroll
    for (int j = 0; j < 8; ++j) {
      int p = tid + (j << 10);
      float dx = xs[p] - cx, dy = ys[p] - cy, dz = zs[p] - cz;
      float d = (dx * dx + dy * dy) + dz * dz;   // contract off: matches numpy ulp-exact
      float nd = fminf(dists[j], d);
      dists[j] = nd;
      if (nd > bv || (nd == bv && p < bi)) { bv = nd; bi = p; }
    }
    #pragma unroll
    for (int s = 1; s < 64; s <<= 1) {
      float ov = __shfl_xor(bv, s); int oi = __shfl_xor(bi, s);
      if (ov > bv || (ov == bv && oi < bi)) { bv = ov; bi = oi; }
    }
    if ((tid & 63) == 0) { rv[tid >> 6] = bv; ri[tid >> 6] = bi; }
    __syncthreads();
    if (tid < 64) {
      float v2 = (tid < 16) ? rv[tid] : -1.0f;
      int i2 = (tid < 16) ? ri[tid] : 0x7fffffff;
      #pragma unroll
      for (int s = 1; s < 16; s <<= 1) {
        float ov = __shfl_xor(v2, s); int oi = __shfl_xor(i2, s);
        if (ov > v2 || (ov == v2 && oi < i2)) { v2 = ov; i2 = oi; }
      }
      if (tid == 0) { curSh = i2; cIdx[b * SGRP + step] = i2; }
    }
    __syncthreads();
    cur = curSh;
  }
}

// ---------------- kNN: 32 smallest d2 per center (set semantics, min-index ties) ----------------
__global__ __launch_bounds__(256) void knn_kernel(const float* __restrict__ xyz,
                                                  const int* __restrict__ cIdx,
                                                  float* __restrict__ nbrDiff,
                                                  float* __restrict__ ctrW,
                                                  float* __restrict__ partials) {
  #pragma clang fp contract(off)
  __shared__ int winners[KNBR];
  __shared__ float rv[4];
  __shared__ int ri[4];
  __shared__ int sWin;
  const int cid = blockIdx.x;
  const int b = cid >> 9;
  const int tid = threadIdx.x;
  const float* xb = xyz + (size_t)b * NPTS * 3;
  const int cI = cIdx[cid];
  const float cx = xb[cI * 3], cy = xb[cI * 3 + 1], cz = xb[cI * 3 + 2];
  const float cs = (cx * cx + cy * cy) + cz * cz;
  float d2[32];
  #pragma unroll
  for (int j = 0; j < 32; ++j) {
    int p = tid + (j << 8);
    float x = xb[p * 3], y = xb[p * 3 + 1], z = xb[p * 3 + 2];
    float ps = (x * x + y * y) + z * z;
    float dot = (cx * x + cy * y) + cz * z;
    d2[j] = (cs + ps) - 2.0f * dot;
  }
  for (int it = 0; it < KNBR; ++it) {
    float bv = 3.402823466e38f; int bi = 0x7fffffff;
    #pragma unroll
    for (int j = 0; j < 32; ++j) {
      int p = tid + (j << 8);
      if (d2[j] < bv || (d2[j] == bv && p < bi)) { bv = d2[j]; bi = p; }
    }
    #pragma unroll
    for (int s = 1; s < 64; s <<= 1) {
      float ov = __shfl_xor(bv, s); int oi = __shfl_xor(bi, s);
      if (ov < bv || (ov == bv && oi < bi)) { bv = ov; bi = oi; }
    }
    if ((tid & 63) == 0) { rv[tid >> 6] = bv; ri[tid >> 6] = bi; }
    __syncthreads();
    if (tid == 0) {
      float wv0 = rv[0]; int wi0 = ri[0];
      for (int w = 1; w < 4; ++w)
        if (rv[w] < wv0 || (rv[w] == wv0 && ri[w] < wi0)) { wv0 = rv[w]; wi0 = ri[w]; }
      winners[it] = wi0; sWin = wi0;
    }
    __syncthreads();
    int w = sWin;
    #pragma unroll
    for (int j = 0; j < 32; ++j)
      if (w == tid + (j << 8)) d2[j] = 3.402823466e38f;
    __syncthreads();
  }
  // gather diffs + per-center stats partials
  float sum = 0.f, sq = 0.f;
  if (tid < KNBR) {
    int w = winners[tid];
    float dx = xb[w * 3] - cx, dy = xb[w * 3 + 1] - cy, dz = xb[w * 3 + 2] - cz;
    size_t o = ((size_t)cid * KNBR + tid) * 3;
    nbrDiff[o + 0] = dx; nbrDiff[o + 1] = dy; nbrDiff[o + 2] = dz;
    sum = (dx + dy) + dz;
    sq = (dx * dx + dy * dy) + dz * dz;
  }
  if (tid < 64) {
    #pragma unroll
    for (int s = 1; s < 64; s <<= 1) { sum += __shfl_xor(sum, s); sq += __shfl_xor(sq, s); }
    if (tid == 0) { partials[cid * 2] = sum; partials[cid * 2 + 1] = sq; }
  }
  if (tid < 3) ctrW[(size_t)cid * 3 + tid] = xb[cI * 3 + tid];
}

// ---------------- per-batch std (ddof=1), deterministic fp64 tree ----------------
__global__ __launch_bounds__(256) void std_kernel(const float* __restrict__ partials,
                                                  float* __restrict__ stdv) {
  __shared__ double sd[256], sq[256];
  const int b = blockIdx.x, t = threadIdx.x;
  int i0 = (b * 512 + t) * 2;
  sd[t] = (double)partials[i0] + (double)partials[i0 + 512];
  sq[t] = (double)partials[i0 + 1] + (double)partials[i0 + 513];
  for (int st = 128; st > 0; st >>= 1) {
    __syncthreads();
    if (t < st) { sd[t] += sd[t + st]; sq[t] += sq[t + st]; }
  }
  if (t == 0) {
    double n = (double)(SGRP * KNBR * 3);
    double mean = sd[0] / n;
    double var = (sq[0] - sd[0] * mean) / (n - 1.0);
    stdv[b] = (float)sqrt(var);
  }
}

// ---------------- fused group MLP (t-net + pre res_block + maxpool) ----------------
// one block = 4 groups (128 l-columns), 8 waves, MFMA 16x16x32 bf16
static __device__ __forceinline__ void gemm_half(const unsigned short* __restrict__ W,
                                                 const unsigned short* ht,
                                                 int oBase, int n0, int r16, int g4,
                                                 f32x4 acc[3][4]) {
  for (int ks = 0; ks < 12; ++ks) {
    const int kOff = ks * 32 + g4 * 8;
    bf16x8 a[3], bb[4];
    #pragma unroll
    for (int i = 0; i < 3; ++i)
      a[i] = *(const bf16x8*)(W + (size_t)(oBase + i * 16 + r16) * CCH + kOff);
    #pragma unroll
    for (int j = 0; j < 4; ++j)
      bb[j] = *(const bf16x8*)(ht + (n0 + j * 16 + r16) * LDSP + kOff);
    #pragma unroll
    for (int i = 0; i < 3; ++i) {
      #pragma unroll
      for (int j = 0; j < 4; ++j)
        acc[i][j] = __builtin_amdgcn_mfma_f32_16x16x32_bf16(a[i], bb[j], acc[i][j], 0, 0, 0);
    }
  }
}

__global__ __launch_bounds__(512) void group_mlp_kernel(
    const float* __restrict__ alpha, const float* __restrict__ beta,
    const float* __restrict__ WtF, const float* __restrict__ btF,
    const unsigned short* __restrict__ W1, const float* __restrict__ b1,
    const unsigned short* __restrict__ W2, const float* __restrict__ b2,
    const float* __restrict__ nbrDiff, const float* __restrict__ ctrW,
    const float* __restrict__ stdv, unsigned short* __restrict__ feat) {
  __shared__ unsigned short ht[128 * LDSP];
  __shared__ float xtw[128 * 8];
  __shared__ float wtl[CCH * 6];
  __shared__ float btl[CCH];

  const int tid = threadIdx.x;
  const int lane = tid & 63, wid = tid >> 6;
  const int r16 = lane & 15, g4 = lane >> 4;
  const int bid = blockIdx.x;
  const int b = bid >> 7;
  const int sBase = (bid & 127) << 2;

  for (int i = tid; i < CCH * 6; i += 512) wtl[i] = WtF[i];
  for (int i = tid; i < CCH; i += 512) btl[i] = btF[i];

  const float inv = 1.0f / (stdv[b] + 1e-5f);
  if (tid < 128) {
    int g = tid >> 5, kk = tid & 31;
    int cid = b * SGRP + sBase + g;
    const float* nb = nbrDiff + ((size_t)cid * KNBR + kk) * 3;
    const float* cc = ctrW + (size_t)cid * 3;
    #pragma unroll
    for (int c = 0; c < 3; ++c) {
      xtw[tid * 8 + c] = alpha[c] * (nb[c] * inv) + beta[c];
      xtw[tid * 8 + 3 + c] = cc[c];
    }
  }
  __syncthreads();

  // conv1 (t-net, K=6) -> h0 bf16 into ht[l][o]
  {
    int l = tid & 127, oi = tid >> 7;
    float xv[6];
    #pragma unroll
    for (int c = 0; c < 6; ++c) xv[c] = xtw[l * 8 + c];
    for (int j = 0; j < 96; ++j) {
      int o = oi * 96 + j;
      float v = btl[o];
      #pragma unroll
      for (int c = 0; c < 6; ++c) v += wtl[o * 6 + c] * xv[c];
      ht[l * LDSP + o] = f2b(fmaxf(v, 0.0f));
    }
  }
  __syncthreads();

  const int oBase = wid * 48;

  // conv2: h1 = relu(W1 h0 + b1), overwrite ht by l-halves (disjoint rows)
  for (int half = 0; half < 2; ++half) {
    const int n0 = half * 64;
    f32x4 acc[3][4];
    #pragma unroll
    for (int i = 0; i < 3; ++i) {
      #pragma unroll
      for (int j = 0; j < 4; ++j) acc[i][j] = (f32x4){0.f, 0.f, 0.f, 0.f};
    }
    gemm_half(W1, ht, oBase, n0, r16, g4, acc);
    __syncthreads();   // all waves done reading this half's h0 rows
    #pragma unroll
    for (int i = 0; i < 3; ++i) {
      int o4 = oBase + i * 16 + g4 * 4;
      float bs0 = b1[o4], bs1 = b1[o4 + 1], bs2 = b1[o4 + 2], bs3 = b1[o4 + 3];
      #pragma unroll
      for (int j = 0; j < 4; ++j) {
        int row = n0 + j * 16 + r16;
        unsigned u0 = pk2(fmaxf(acc[i][j][0] + bs0, 0.f), fmaxf(acc[i][j][1] + bs1, 0.f));
        unsigned u1 = pk2(fmaxf(acc[i][j][2] + bs2, 0.f), fmaxf(acc[i][j][3] + bs3, 0.f));
        *(uint2*)(ht + row * LDSP + o4) = make_uint2(u0, u1);
      }
    }
    __syncthreads();
  }

  // conv3 + bias + residual(h0 recomputed) + relu + maxpool over K=32
  for (int half = 0; half < 2; ++half) {
    const int n0 = half * 64;
    f32x4 acc[3][4];
    #pragma unroll
    for (int i = 0; i < 3; ++i) {
      #pragma unroll
      for (int j = 0; j < 4; ++j) acc[i][j] = (f32x4){0.f, 0.f, 0.f, 0.f};
    }
    gemm_half(W2, ht, oBase, n0, r16, g4, acc);

    float bias2[3][4];
    #pragma unroll
    for (int i = 0; i < 3; ++i) {
      int o4 = oBase + i * 16 + g4 * 4;
      #pragma unroll
      for (int r = 0; r < 4; ++r) bias2[i][r] = b2[o4 + r];
    }
    float mx[3][2][4];
    #pragma unroll
    for (int i = 0; i < 3; ++i) {
      #pragma unroll
      for (int gg = 0; gg < 2; ++gg) {
        #pragma unroll
        for (int r = 0; r < 4; ++r) mx[i][gg][r] = 0.f;   // values are relu'd (>=0)
      }
    }
    #pragma unroll
    for (int j = 0; j < 4; ++j) {
      int l = n0 + j * 16 + r16;
      float xv[6];
      #pragma unroll
      for (int c = 0; c < 6; ++c) xv[c] = xtw[l * 8 + c];
      #pragma unroll
      for (int i = 0; i < 3; ++i) {
        int o4 = oBase + i * 16 + g4 * 4;
        #pragma unroll
        for (int r = 0; r < 4; ++r) {
          float h0 = btl[o4 + r];
          #pragma unroll
          for (int c = 0; c < 6; ++c) h0 += wtl[(o4 + r) * 6 + c] * xv[c];
          h0 = fmaxf(h0, 0.f);
          float v = fmaxf(acc[i][j][r] + bias2[i][r] + h0, 0.f);
          mx[i][j >> 1][r] = fmaxf(mx[i][j >> 1][r], v);
        }
      }
    }
    #pragma unroll
    for (int i = 0; i < 3; ++i) {
      #pragma unroll
      for (int gg = 0; gg < 2; ++gg) {
        float m0 = mx[i][gg][0], m1 = mx[i][gg][1], m2 = mx[i][gg][2], m3 = mx[i][gg][3];
        #pragma unroll
        for (int s = 1; s < 16; s <<= 1) {
          m0 = fmaxf(m0, __shfl_xor(m0, s));
          m1 = fmaxf(m1, __shfl_xor(m1, s));
          m2 = fmaxf(m2, __shfl_xor(m2, s));
          m3 = fmaxf(m3, __shfl_xor(m3, s));
        }
        if (r16 == 0) {
          int sIdx = sBase + half * 2 + gg;
          size_t fi = ((size_t)(b * SGRP + sIdx)) * CCH + oBase + i * 16 + g4 * 4;
          *(uint2*)(feat + fi) = make_uint2(pk2(m0, m1), pk2(m2, m3));
        }
      }
    }
  }
}

// ---------------- pos res_block on feat (B,384,512) + final transpose to (B,S,C) fp32 ----------------
__global__ __launch_bounds__(256) void pos_kernel(const unsigned short* __restrict__ feat,
                                                  const unsigned short* __restrict__ Wp1,
                                                  const float* __restrict__ bp1,
                                                  const unsigned short* __restrict__ Wp2,
                                                  const float* __restrict__ bp2,
                                                  float* __restrict__ out) {
  __shared__ unsigned short h1[16 * LDSP];
  const int tid = threadIdx.x;
  const int lane = tid & 63, wid = tid >> 6;
  const int r16 = lane & 15, g4 = lane >> 4;
  const int bid = blockIdx.x;
  const int b = bid >> 5;
  const int s0 = (bid & 31) << 4;
  const size_t rowBase = ((size_t)(b * SGRP + s0 + r16)) * CCH;

  f32x4 acc[6];
  #pragma unroll
  for (int i = 0; i < 6; ++i) acc[i] = (f32x4){0.f, 0.f, 0.f, 0.f};
  for (int ks = 0; ks < 12; ++ks) {
    const int kOff = ks * 32 + g4 * 8;
    bf16x8 bfr = *(const bf16x8*)(feat + rowBase + kOff);
    #pragma unroll
    for (int i = 0; i < 6; ++i) {
      bf16x8 a = *(const bf16x8*)(Wp1 + (size_t)(wid * 96 + i * 16 + r16) * CCH + kOff);
      acc[i] = __builtin_amdgcn_mfma_f32_16x16x32_bf16(a, bfr, acc[i], 0, 0, 0);
    }
  }
  #pragma unroll
  for (int i = 0; i < 6; ++i) {
    int o4 = wid * 96 + i * 16 + g4 * 4;
    unsigned u0 = pk2(fmaxf(acc[i][0] + bp1[o4 + 0], 0.f), fmaxf(acc[i][1] + bp1[o4 + 1], 0.f));
    unsigned u1 = pk2(fmaxf(acc[i][2] + bp1[o4 + 2], 0.f), fmaxf(acc[i][3] + bp1[o4 + 3], 0.f));
    *(uint2*)(h1 + r16 * LDSP + o4) = make_uint2(u0, u1);
  }
  __syncthreads();

  f32x4 acc2[6];
  #pragma unroll
  for (int i = 0; i < 6; ++i) acc2[i] = (f32x4){0.f, 0.f, 0.f, 0.f};
  for (int ks = 0; ks < 12; ++ks) {
    const int kOff = ks * 32 + g4 * 8;
    bf16x8 bfr = *(const bf16x8*)(h1 + r16 * LDSP + kOff);
    #pragma unroll
    for (int i = 0; i < 6; ++i) {
      bf16x8 a = *(const bf16x8*)(Wp2 + (size_t)(wid * 96 + i * 16 + r16) * CCH + kOff);
      acc2[i] = __builtin_amdgcn_mfma_f32_16x16x32_bf16(a, bfr, acc2[i], 0, 0, 0);
    }
  }
  #pragma unroll
  for (int i = 0; i < 6; ++i) {
    int o4 = wid * 96 + i * 16 + g4 * 4;
    uint2 rr = *(const uint2*)(feat + rowBase + o4);
    float4 v;
    v.x = fmaxf(acc2[i][0] + bp2[o4 + 0] + b2f((unsigned short)(rr.x & 0xffff)), 0.f);
    v.y = fmaxf(acc2[i][1] + bp2[o4 + 1] + b2f((unsigned short)(rr.x >> 16)), 0.f);
    v.z = fmaxf(acc2[i][2] + bp2[o4 + 2] + b2f((unsigned short)(rr.y & 0xffff)), 0.f);
    v.w = fmaxf(acc2[i][3] + bp2[o4 + 3] + b2f((unsigned short)(rr.y >> 16)), 0.f);
    *(float4*)(out + rowBase + o4) = v;
  }
}

// ---------------- launch ----------------
extern "C" void kernel_launch(void* const* d_in, const int* in_sizes, int n_in,
                              void* d_out, int out_size, void* d_ws, size_t ws_size,
                              hipStream_t stream) {
  (void)in_sizes; (void)n_in; (void)out_size; (void)ws_size;
  const float* xyz   = (const float*)d_in[0];
  const float* alpha = (const float*)d_in[1];
  const float* beta  = (const float*)d_in[2];
  const float* Wt    = (const float*)d_in[3];
  const float* bt    = (const float*)d_in[4];
  const float* gt    = (const float*)d_in[5];
  const float* bbt   = (const float*)d_in[6];
  const float* Wpre1 = (const float*)d_in[7];
  const float* bpre1 = (const float*)d_in[8];
  const float* gpre1 = (const float*)d_in[9];
  const float* bbpre1= (const float*)d_in[10];
  const float* Wpre2 = (const float*)d_in[11];
  const float* bpre2 = (const float*)d_in[12];
  const float* gpre2 = (const float*)d_in[13];
  const float* bbpre2= (const float*)d_in[14];
  const float* Wpos1 = (const float*)d_in[15];
  const float* bpos1 = (const float*)d_in[16];
  const float* gpos1 = (const float*)d_in[17];
  const float* bbpos1= (const float*)d_in[18];
  const float* Wpos2 = (const float*)d_in[19];
  const float* bpos2 = (const float*)d_in[20];
  const float* gpos2 = (const float*)d_in[21];
  const float* bbpos2= (const float*)d_in[22];

  char* ws = (char*)d_ws;
  size_t off = 0;
  auto alloc = [&](size_t bytes) -> void* {
    void* p = ws + off;
    off += (bytes + 255) & ~(size_t)255;
    return p;
  };
  float* WtF = (float*)alloc(CCH * 6 * 4);
  float* btF = (float*)alloc(CCH * 4);
  unsigned short* W1 = (unsigned short*)alloc(CCH * CCH * 2);
  float* b1 = (float*)alloc(CCH * 4);
  unsigned short* W2 = (unsigned short*)alloc(CCH * CCH * 2);
  float* b2 = (float*)alloc(CCH * 4);
  unsigned short* Wp1 = (unsigned short*)alloc(CCH * CCH * 2);
  float* bp1 = (float*)alloc(CCH * 4);
  unsigned short* Wp2 = (unsigned short*)alloc(CCH * CCH * 2);
  float* bp2 = (float*)alloc(CCH * 4);
  int* cIdx = (int*)alloc(8 * SGRP * 4);
  float* ctrW = (float*)alloc(8 * SGRP * 3 * 4);
  float* nbrD = (float*)alloc((size_t)8 * SGRP * KNBR * 3 * 4);
  float* partials = (float*)alloc(8 * SGRP * 2 * 4);
  float* stdv = (float*)alloc(8 * 4);
  unsigned short* feat = (unsigned short*)alloc((size_t)8 * SGRP * CCH * 2);

  fold_w_f32<<<CCH, 64, 0, stream>>>(Wt, bt, gt, bbt, WtF, btF, 6);
  fold_w_bf16<<<CCH, 128, 0, stream>>>(Wpre1, bpre1, gpre1, bbpre1, W1, b1, CCH);
  fold_w_bf16<<<CCH, 128, 0, stream>>>(Wpre2, bpre2, gpre2, bbpre2, W2, b2, CCH);
  fold_w_bf16<<<CCH, 128, 0, stream>>>(Wpos1, bpos1, gpos1, bbpos1, Wp1, bp1, CCH);
  fold_w_bf16<<<CCH, 128, 0, stream>>>(Wpos2, bpos2, gpos2, bbpos2, Wp2, bp2, CCH);

  fps_kernel<<<8, 1024, 0, stream>>>(xyz, cIdx);
  knn_kernel<<<8 * SGRP, 256, 0, stream>>>(xyz, cIdx, nbrD, ctrW, partials);
  std_kernel<<<8, 256, 0, stream>>>(partials, stdv);
  group_mlp_kernel<<<1024, 512, 0, stream>>>(alpha, beta, WtF, btF, W1, b1, W2, b2,
                                             nbrD, ctrW, stdv, feat);
  pos_kernel<<<256, 256, 0, stream>>>(feat, Wp1, bp1, Wp2, bp2, (float*)d_out);
}

// Round 2
// 1289.761 us; speedup vs baseline: 1.3757x; 1.3757x over previous
//
#include <hip/hip_runtime.h>
#include <hip/hip_bf16.h>
#include <math.h>

typedef __bf16 bf16x8 __attribute__((ext_vector_type(8)));
typedef float f32x4 __attribute__((ext_vector_type(4)));

#define NPTS 8192
#define SGRP 512
#define KNBR 32
#define CCH 384
#define LDSP 392   // padded ushort row stride for [l][c] LDS tiles

static __device__ __forceinline__ unsigned short f2b(float f) {
  union { float f; unsigned u; } v; v.f = f;
  return (unsigned short)((v.u + 0x7fffu + ((v.u >> 16) & 1u)) >> 16);
}
static __device__ __forceinline__ float b2f(unsigned short u) {
  union { unsigned u; float f; } v; v.u = ((unsigned)u) << 16;
  return v.f;
}
static __device__ __forceinline__ unsigned pk2(float a, float b) {
  return (unsigned)f2b(a) | ((unsigned)f2b(b) << 16);
}

// ---------------- weight folding: bn(conv(x)) = (W*s)x + (b*s+bb) ----------------
struct FoldArgs {
  const float *W, *b, *g, *bb;
  unsigned short* Wd;
  float* bd;
};
__global__ void fold4_bf16(FoldArgs a0, FoldArgs a1, FoldArgs a2, FoldArgs a3) {
  FoldArgs a = (blockIdx.y == 0) ? a0 : (blockIdx.y == 1) ? a1 : (blockIdx.y == 2) ? a2 : a3;
  int o = blockIdx.x;
  float sc = a.g[o] / sqrtf(1.0f + 1e-5f);
  for (int c = threadIdx.x; c < CCH; c += blockDim.x)
    a.Wd[o * CCH + c] = f2b(a.W[o * CCH + c] * sc);
  if (threadIdx.x == 0) a.bd[o] = a.b[o] * sc + a.bb[o];
}
__global__ void fold_w_f32(const float* __restrict__ W, const float* __restrict__ b,
                           const float* __restrict__ g, const float* __restrict__ bb,
                           float* __restrict__ Wd, float* __restrict__ bd, int Cin) {
  int o = blockIdx.x;
  float sc = g[o] / sqrtf(1.0f + 1e-5f);
  for (int c = threadIdx.x; c < Cin; c += blockDim.x)
    Wd[o * Cin + c] = W[o * Cin + c] * sc;
  if (threadIdx.x == 0) bd[o] = b[o] * sc + bb[o];
}

// ---------------- FPS v2: points in registers, 1 barrier/step, u64-key LDS atomics ----
// key = (float_bits(dist) << 32) | (8191 - idx); atomicMax => argmax, ties -> lowest idx.
__global__ __launch_bounds__(512) void fps_kernel(const float* __restrict__ xyz,
                                                  int* __restrict__ cIdx) {
  #pragma clang fp contract(off)
  __shared__ float xs[NPTS], ys[NPTS], zs[NPTS];
  __shared__ unsigned long long keyBuf[4];
  const int b = blockIdx.x, tid = threadIdx.x;
  const float* xb = xyz + (size_t)b * NPTS * 3;

  float X[16], Y[16], Z[16], D[16];
  #pragma unroll
  for (int j = 0; j < 16; ++j) {
    int p = tid + (j << 9);
    float x = xb[p * 3 + 0], y = xb[p * 3 + 1], z = xb[p * 3 + 2];
    X[j] = x; Y[j] = y; Z[j] = z;
    D[j] = __builtin_inff();
    xs[p] = x; ys[p] = y; zs[p] = z;
  }
  if (tid < 4) keyBuf[tid] = 0ull;
  if (tid == 0) cIdx[b * SGRP] = 0;
  __syncthreads();
  float cx = xs[0], cy = ys[0], cz = zs[0];

  for (int step = 1; step < SGRP; ++step) {
    if (tid == 0) keyBuf[(step + 2) & 3] = 0ull;   // slot reused 2 steps later; barrier-ordered
    float bv = -1.0f; int bi = 0;
    #pragma unroll
    for (int j = 0; j < 16; ++j) {
      float dx = X[j] - cx, dy = Y[j] - cy, dz = Z[j] - cz;
      float d = (dx * dx + dy * dy) + dz * dz;   // contract off: numpy ulp-exact
      float nd = fminf(D[j], d);
      D[j] = nd;
      if (nd > bv) { bv = nd; bi = tid + (j << 9); }   // strict >: keeps lowest p in-thread
    }
    #pragma unroll
    for (int s = 1; s < 64; s <<= 1) {
      float ov = __shfl_xor(bv, s); int oi = __shfl_xor(bi, s);
      if (ov > bv || (ov == bv && oi < bi)) { bv = ov; bi = oi; }
    }
    if ((tid & 63) == 0) {
      unsigned long long key =
          (((unsigned long long)__float_as_uint(bv)) << 32) | (unsigned long long)(8191 - bi);
      atomicMax(&keyBuf[step & 3], key);
    }
    __syncthreads();
    unsigned long long k = keyBuf[step & 3];
    int gi = 8191 - (int)(k & 0x1FFFu);
    if (tid == 0) cIdx[b * SGRP + step] = gi;
    cx = xs[gi]; cy = ys[gi]; cz = zs[gi];   // LDS broadcast
  }
}

// ---------------- kNN v2: cached per-thread min, winner-only rescan, 1 barrier/iter ----
__global__ __launch_bounds__(256) void knn_kernel(const float* __restrict__ xyz,
                                                  const int* __restrict__ cIdx,
                                                  float* __restrict__ nbrDiff,
                                                  float* __restrict__ ctrW,
                                                  float* __restrict__ partials) {
  #pragma clang fp contract(off)
  __shared__ unsigned long long keyBuf[4];
  __shared__ int winners[KNBR];
  const int cid = blockIdx.x;
  const int b = cid >> 9;
  const int tid = threadIdx.x;
  const float* xb = xyz + (size_t)b * NPTS * 3;
  const int cI = cIdx[cid];
  const float cx = xb[cI * 3], cy = xb[cI * 3 + 1], cz = xb[cI * 3 + 2];
  const float cs = (cx * cx + cy * cy) + cz * cz;

  float d2[32];
  float mv = __builtin_inff(); int mi = 0;
  #pragma unroll
  for (int j = 0; j < 32; ++j) {
    int p = tid + (j << 8);
    float x = xb[p * 3], y = xb[p * 3 + 1], z = xb[p * 3 + 2];
    float ps = (x * x + y * y) + z * z;
    float dot = (cx * x + cy * y) + cz * z;
    d2[j] = (cs + ps) - 2.0f * dot;
    if (d2[j] < mv) { mv = d2[j]; mi = p; }   // strict <: lowest p on tie
  }
  if (tid < 4) keyBuf[tid] = 0xFFFFFFFFFFFFFFFFull;
  __syncthreads();

  for (int it = 0; it < KNBR; ++it) {
    if (tid == 0) keyBuf[(it + 2) & 3] = 0xFFFFFFFFFFFFFFFFull;
    float bv = mv; int bi = mi;
    #pragma unroll
    for (int s = 1; s < 64; s <<= 1) {
      float ov = __shfl_xor(bv, s); int oi = __shfl_xor(bi, s);
      if (ov < bv || (ov == bv && oi < bi)) { bv = ov; bi = oi; }
    }
    if ((tid & 63) == 0) {
      unsigned u = __float_as_uint(bv);
      unsigned m = u ^ (unsigned)(((int)u >> 31) | 0x80000000);   // monotone float->uint
      unsigned long long key = (((unsigned long long)m) << 32) | (unsigned long long)bi;
      atomicMin(&keyBuf[it & 3], key);
    }
    __syncthreads();
    unsigned long long k = keyBuf[it & 3];
    int wi = (int)(k & 0x1FFFu);
    if (tid == 0) winners[it] = wi;
    if (tid == (wi & 255)) {     // only the owner rescans its 32 values
      #pragma unroll
      for (int j = 0; j < 32; ++j)
        if (wi == tid + (j << 8)) d2[j] = __builtin_inff();
      mv = __builtin_inff(); mi = 0;
      #pragma unroll
      for (int j = 0; j < 32; ++j)
        if (d2[j] < mv) { mv = d2[j]; mi = tid + (j << 8); }
    }
  }
  __syncthreads();

  // gather diffs + per-center stats partials (identical to passing v1)
  float sum = 0.f, sq = 0.f;
  if (tid < KNBR) {
    int w = winners[tid];
    float dx = xb[w * 3] - cx, dy = xb[w * 3 + 1] - cy, dz = xb[w * 3 + 2] - cz;
    size_t o = ((size_t)cid * KNBR + tid) * 3;
    nbrDiff[o + 0] = dx; nbrDiff[o + 1] = dy; nbrDiff[o + 2] = dz;
    sum = (dx + dy) + dz;
    sq = (dx * dx + dy * dy) + dz * dz;
  }
  if (tid < 64) {
    #pragma unroll
    for (int s = 1; s < 64; s <<= 1) { sum += __shfl_xor(sum, s); sq += __shfl_xor(sq, s); }
    if (tid == 0) { partials[cid * 2] = sum; partials[cid * 2 + 1] = sq; }
  }
  if (tid < 3) ctrW[(size_t)cid * 3 + tid] = xb[cI * 3 + tid];
}

// ---------------- per-batch std (ddof=1), deterministic fp64 tree ----------------
__global__ __launch_bounds__(256) void std_kernel(const float* __restrict__ partials,
                                                  float* __restrict__ stdv) {
  __shared__ double sd[256], sq[256];
  const int b = blockIdx.x, t = threadIdx.x;
  int i0 = (b * 512 + t) * 2;
  sd[t] = (double)partials[i0] + (double)partials[i0 + 512];
  sq[t] = (double)partials[i0 + 1] + (double)partials[i0 + 513];
  for (int st = 128; st > 0; st >>= 1) {
    __syncthreads();
    if (t < st) { sd[t] += sd[t + st]; sq[t] += sq[t + st]; }
  }
  if (t == 0) {
    double n = (double)(SGRP * KNBR * 3);
    double mean = sd[0] / n;
    double var = (sq[0] - sd[0] * mean) / (n - 1.0);
    stdv[b] = (float)sqrt(var);
  }
}

// ---------------- fused group MLP (t-net + pre res_block + maxpool) ----------------
// one block = 4 groups (128 l-columns), 8 waves, MFMA 16x16x32 bf16
static __device__ __forceinline__ void gemm_half(const unsigned short* __restrict__ W,
                                                 const unsigned short* ht,
                                                 int oBase, int n0, int r16, int g4,
                                                 f32x4 acc[3][4]) {
  for (int ks = 0; ks < 12; ++ks) {
    const int kOff = ks * 32 + g4 * 8;
    bf16x8 a[3], bb[4];
    #pragma unroll
    for (int i = 0; i < 3; ++i)
      a[i] = *(const bf16x8*)(W + (size_t)(oBase + i * 16 + r16) * CCH + kOff);
    #pragma unroll
    for (int j = 0; j < 4; ++j)
      bb[j] = *(const bf16x8*)(ht + (n0 + j * 16 + r16) * LDSP + kOff);
    #pragma unroll
    for (int i = 0; i < 3; ++i) {
      #pragma unroll
      for (int j = 0; j < 4; ++j)
        acc[i][j] = __builtin_amdgcn_mfma_f32_16x16x32_bf16(a[i], bb[j], acc[i][j], 0, 0, 0);
    }
  }
}

__global__ __launch_bounds__(512) void group_mlp_kernel(
    const float* __restrict__ alpha, const float* __restrict__ beta,
    const float* __restrict__ WtF, const float* __restrict__ btF,
    const unsigned short* __restrict__ W1, const float* __restrict__ b1,
    const unsigned short* __restrict__ W2, const float* __restrict__ b2,
    const float* __restrict__ nbrDiff, const float* __restrict__ ctrW,
    const float* __restrict__ stdv, unsigned short* __restrict__ feat) {
  __shared__ unsigned short ht[128 * LDSP];
  __shared__ float xtw[128 * 8];
  __shared__ float wtl[CCH * 6];
  __shared__ float btl[CCH];

  const int tid = threadIdx.x;
  const int lane = tid & 63, wid = tid >> 6;
  const int r16 = lane & 15, g4 = lane >> 4;
  const int bid = blockIdx.x;
  const int b = bid >> 7;
  const int sBase = (bid & 127) << 2;

  for (int i = tid; i < CCH * 6; i += 512) wtl[i] = WtF[i];
  for (int i = tid; i < CCH; i += 512) btl[i] = btF[i];

  const float inv = 1.0f / (stdv[b] + 1e-5f);
  if (tid < 128) {
    int g = tid >> 5, kk = tid & 31;
    int cid = b * SGRP + sBase + g;
    const float* nb = nbrDiff + ((size_t)cid * KNBR + kk) * 3;
    const float* cc = ctrW + (size_t)cid * 3;
    #pragma unroll
    for (int c = 0; c < 3; ++c) {
      xtw[tid * 8 + c] = alpha[c] * (nb[c] * inv) + beta[c];
      xtw[tid * 8 + 3 + c] = cc[c];
    }
  }
  __syncthreads();

  // conv1 (t-net, K=6) -> h0 bf16 into ht[l][o]
  {
    int l = tid & 127, oi = tid >> 7;
    float xv[6];
    #pragma unroll
    for (int c = 0; c < 6; ++c) xv[c] = xtw[l * 8 + c];
    for (int j = 0; j < 96; ++j) {
      int o = oi * 96 + j;
      float v = btl[o];
      #pragma unroll
      for (int c = 0; c < 6; ++c) v += wtl[o * 6 + c] * xv[c];
      ht[l * LDSP + o] = f2b(fmaxf(v, 0.0f));
    }
  }
  __syncthreads();

  const int oBase = wid * 48;

  // conv2: h1 = relu(W1 h0 + b1), overwrite ht by l-halves (disjoint rows)
  for (int half = 0; half < 2; ++half) {
    const int n0 = half * 64;
    f32x4 acc[3][4];
    #pragma unroll
    for (int i = 0; i < 3; ++i) {
      #pragma unroll
      for (int j = 0; j < 4; ++j) acc[i][j] = (f32x4){0.f, 0.f, 0.f, 0.f};
    }
    gemm_half(W1, ht, oBase, n0, r16, g4, acc);
    __syncthreads();   // all waves done reading this half's h0 rows
    #pragma unroll
    for (int i = 0; i < 3; ++i) {
      int o4 = oBase + i * 16 + g4 * 4;
      float bs0 = b1[o4], bs1 = b1[o4 + 1], bs2 = b1[o4 + 2], bs3 = b1[o4 + 3];
      #pragma unroll
      for (int j = 0; j < 4; ++j) {
        int row = n0 + j * 16 + r16;
        unsigned u0 = pk2(fmaxf(acc[i][j][0] + bs0, 0.f), fmaxf(acc[i][j][1] + bs1, 0.f));
        unsigned u1 = pk2(fmaxf(acc[i][j][2] + bs2, 0.f), fmaxf(acc[i][j][3] + bs3, 0.f));
        *(uint2*)(ht + row * LDSP + o4) = make_uint2(u0, u1);
      }
    }
    __syncthreads();
  }

  // conv3 + bias + residual(h0 recomputed) + relu + maxpool over K=32
  for (int half = 0; half < 2; ++half) {
    const int n0 = half * 64;
    f32x4 acc[3][4];
    #pragma unroll
    for (int i = 0; i < 3; ++i) {
      #pragma unroll
      for (int j = 0; j < 4; ++j) acc[i][j] = (f32x4){0.f, 0.f, 0.f, 0.f};
    }
    gemm_half(W2, ht, oBase, n0, r16, g4, acc);

    float bias2[3][4];
    #pragma unroll
    for (int i = 0; i < 3; ++i) {
      int o4 = oBase + i * 16 + g4 * 4;
      #pragma unroll
      for (int r = 0; r < 4; ++r) bias2[i][r] = b2[o4 + r];
    }
    float mx[3][2][4];
    #pragma unroll
    for (int i = 0; i < 3; ++i) {
      #pragma unroll
      for (int gg = 0; gg < 2; ++gg) {
        #pragma unroll
        for (int r = 0; r < 4; ++r) mx[i][gg][r] = 0.f;   // values are relu'd (>=0)
      }
    }
    #pragma unroll
    for (int j = 0; j < 4; ++j) {
      int l = n0 + j * 16 + r16;
      float xv[6];
      #pragma unroll
      for (int c = 0; c < 6; ++c) xv[c] = xtw[l * 8 + c];
      #pragma unroll
      for (int i = 0; i < 3; ++i) {
        int o4 = oBase + i * 16 + g4 * 4;
        #pragma unroll
        for (int r = 0; r < 4; ++r) {
          float h0 = btl[o4 + r];
          #pragma unroll
          for (int c = 0; c < 6; ++c) h0 += wtl[(o4 + r) * 6 + c] * xv[c];
          h0 = fmaxf(h0, 0.f);
          float v = fmaxf(acc[i][j][r] + bias2[i][r] + h0, 0.f);
          mx[i][j >> 1][r] = fmaxf(mx[i][j >> 1][r], v);
        }
      }
    }
    #pragma unroll
    for (int i = 0; i < 3; ++i) {
      #pragma unroll
      for (int gg = 0; gg < 2; ++gg) {
        float m0 = mx[i][gg][0], m1 = mx[i][gg][1], m2 = mx[i][gg][2], m3 = mx[i][gg][3];
        #pragma unroll
        for (int s = 1; s < 16; s <<= 1) {
          m0 = fmaxf(m0, __shfl_xor(m0, s));
          m1 = fmaxf(m1, __shfl_xor(m1, s));
          m2 = fmaxf(m2, __shfl_xor(m2, s));
          m3 = fmaxf(m3, __shfl_xor(m3, s));
        }
        if (r16 == 0) {
          int sIdx = sBase + half * 2 + gg;
          size_t fi = ((size_t)(b * SGRP + sIdx)) * CCH + oBase + i * 16 + g4 * 4;
          *(uint2*)(feat + fi) = make_uint2(pk2(m0, m1), pk2(m2, m3));
        }
      }
    }
  }
}

// ---------------- pos res_block on feat (B,384,512) + final transpose to (B,S,C) fp32 ----------------
__global__ __launch_bounds__(256) void pos_kernel(const unsigned short* __restrict__ feat,
                                                  const unsigned short* __restrict__ Wp1,
                                                  const float* __restrict__ bp1,
                                                  const unsigned short* __restrict__ Wp2,
                                                  const float* __restrict__ bp2,
                                                  float* __restrict__ out) {
  __shared__ unsigned short h1[16 * LDSP];
  const int tid = threadIdx.x;
  const int lane = tid & 63, wid = tid >> 6;
  const int r16 = lane & 15, g4 = lane >> 4;
  const int bid = blockIdx.x;
  const int b = bid >> 5;
  const int s0 = (bid & 31) << 4;
  const size_t rowBase = ((size_t)(b * SGRP + s0 + r16)) * CCH;

  f32x4 acc[6];
  #pragma unroll
  for (int i = 0; i < 6; ++i) acc[i] = (f32x4){0.f, 0.f, 0.f, 0.f};
  for (int ks = 0; ks < 12; ++ks) {
    const int kOff = ks * 32 + g4 * 8;
    bf16x8 bfr = *(const bf16x8*)(feat + rowBase + kOff);
    #pragma unroll
    for (int i = 0; i < 6; ++i) {
      bf16x8 a = *(const bf16x8*)(Wp1 + (size_t)(wid * 96 + i * 16 + r16) * CCH + kOff);
      acc[i] = __builtin_amdgcn_mfma_f32_16x16x32_bf16(a, bfr, acc[i], 0, 0, 0);
    }
  }
  #pragma unroll
  for (int i = 0; i < 6; ++i) {
    int o4 = wid * 96 + i * 16 + g4 * 4;
    unsigned u0 = pk2(fmaxf(acc[i][0] + bp1[o4 + 0], 0.f), fmaxf(acc[i][1] + bp1[o4 + 1], 0.f));
    unsigned u1 = pk2(fmaxf(acc[i][2] + bp1[o4 + 2], 0.f), fmaxf(acc[i][3] + bp1[o4 + 3], 0.f));
    *(uint2*)(h1 + r16 * LDSP + o4) = make_uint2(u0, u1);
  }
  __syncthreads();

  f32x4 acc2[6];
  #pragma unroll
  for (int i = 0; i < 6; ++i) acc2[i] = (f32x4){0.f, 0.f, 0.f, 0.f};
  for (int ks = 0; ks < 12; ++ks) {
    const int kOff = ks * 32 + g4 * 8;
    bf16x8 bfr = *(const bf16x8*)(h1 + r16 * LDSP + kOff);
    #pragma unroll
    for (int i = 0; i < 6; ++i) {
      bf16x8 a = *(const bf16x8*)(Wp2 + (size_t)(wid * 96 + i * 16 + r16) * CCH + kOff);
      acc2[i] = __builtin_amdgcn_mfma_f32_16x16x32_bf16(a, bfr, acc2[i], 0, 0, 0);
    }
  }
  #pragma unroll
  for (int i = 0; i < 6; ++i) {
    int o4 = wid * 96 + i * 16 + g4 * 4;
    uint2 rr = *(const uint2*)(feat + rowBase + o4);
    float4 v;
    v.x = fmaxf(acc2[i][0] + bp2[o4 + 0] + b2f((unsigned short)(rr.x & 0xffff)), 0.f);
    v.y = fmaxf(acc2[i][1] + bp2[o4 + 1] + b2f((unsigned short)(rr.x >> 16)), 0.f);
    v.z = fmaxf(acc2[i][2] + bp2[o4 + 2] + b2f((unsigned short)(rr.y & 0xffff)), 0.f);
    v.w = fmaxf(acc2[i][3] + bp2[o4 + 3] + b2f((unsigned short)(rr.y >> 16)), 0.f);
    *(float4*)(out + rowBase + o4) = v;
  }
}

// ---------------- launch ----------------
extern "C" void kernel_launch(void* const* d_in, const int* in_sizes, int n_in,
                              void* d_out, int out_size, void* d_ws, size_t ws_size,
                              hipStream_t stream) {
  (void)in_sizes; (void)n_in; (void)out_size; (void)ws_size;
  const float* xyz   = (const float*)d_in[0];
  const float* alpha = (const float*)d_in[1];
  const float* beta  = (const float*)d_in[2];
  const float* Wt    = (const float*)d_in[3];
  const float* bt    = (const float*)d_in[4];
  const float* gt    = (const float*)d_in[5];
  const float* bbt   = (const float*)d_in[6];
  const float* Wpre1 = (const float*)d_in[7];
  const float* bpre1 = (const float*)d_in[8];
  const float* gpre1 = (const float*)d_in[9];
  const float* bbpre1= (const float*)d_in[10];
  const float* Wpre2 = (const float*)d_in[11];
  const float* bpre2 = (const float*)d_in[12];
  const float* gpre2 = (const float*)d_in[13];
  const float* bbpre2= (const float*)d_in[14];
  const float* Wpos1 = (const float*)d_in[15];
  const float* bpos1 = (const float*)d_in[16];
  const float* gpos1 = (const float*)d_in[17];
  const float* bbpos1= (const float*)d_in[18];
  const float* Wpos2 = (const float*)d_in[19];
  const float* bpos2 = (const float*)d_in[20];
  const float* gpos2 = (const float*)d_in[21];
  const float* bbpos2= (const float*)d_in[22];

  char* ws = (char*)d_ws;
  size_t off = 0;
  auto alloc = [&](size_t bytes) -> void* {
    void* p = ws + off;
    off += (bytes + 255) & ~(size_t)255;
    return p;
  };
  float* WtF = (float*)alloc(CCH * 6 * 4);
  float* btF = (float*)alloc(CCH * 4);
  unsigned short* W1 = (unsigned short*)alloc(CCH * CCH * 2);
  float* b1 = (float*)alloc(CCH * 4);
  unsigned short* W2 = (unsigned short*)alloc(CCH * CCH * 2);
  float* b2 = (float*)alloc(CCH * 4);
  unsigned short* Wp1 = (unsigned short*)alloc(CCH * CCH * 2);
  float* bp1 = (float*)alloc(CCH * 4);
  unsigned short* Wp2 = (unsigned short*)alloc(CCH * CCH * 2);
  float* bp2 = (float*)alloc(CCH * 4);
  int* cIdx = (int*)alloc(8 * SGRP * 4);
  float* ctrW = (float*)alloc(8 * SGRP * 3 * 4);
  float* nbrD = (float*)alloc((size_t)8 * SGRP * KNBR * 3 * 4);
  float* partials = (float*)alloc(8 * SGRP * 2 * 4);
  float* stdv = (float*)alloc(8 * 4);
  unsigned short* feat = (unsigned short*)alloc((size_t)8 * SGRP * CCH * 2);

  fold_w_f32<<<CCH, 64, 0, stream>>>(Wt, bt, gt, bbt, WtF, btF, 6);
  FoldArgs fa0{Wpre1, bpre1, gpre1, bbpre1, W1, b1};
  FoldArgs fa1{Wpre2, bpre2, gpre2, bbpre2, W2, b2};
  FoldArgs fa2{Wpos1, bpos1, gpos1, bbpos1, Wp1, bp1};
  FoldArgs fa3{Wpos2, bpos2, gpos2, bbpos2, Wp2, bp2};
  fold4_bf16<<<dim3(CCH, 4), 128, 0, stream>>>(fa0, fa1, fa2, fa3);

  fps_kernel<<<8, 512, 0, stream>>>(xyz, cIdx);
  knn_kernel<<<8 * SGRP, 256, 0, stream>>>(xyz, cIdx, nbrD, ctrW, partials);
  std_kernel<<<8, 256, 0, stream>>>(partials, stdv);
  group_mlp_kernel<<<1024, 512, 0, stream>>>(alpha, beta, WtF, btF, W1, b1, W2, b2,
                                             nbrD, ctrW, stdv, feat);
  pos_kernel<<<256, 256, 0, stream>>>(feat, Wp1, bp1, Wp2, bp2, (float*)d_out);
}

// Round 3
// 1075.781 us; speedup vs baseline: 1.6494x; 1.1989x over previous
//
#include <hip/hip_runtime.h>
#include <hip/hip_bf16.h>
#include <math.h>

typedef __bf16 bf16x8 __attribute__((ext_vector_type(8)));
typedef float f32x4 __attribute__((ext_vector_type(4)));

#define NPTS 8192
#define SGRP 512
#define KNBR 32
#define CCH 384
#define LDSP 392   // padded ushort row stride for [l][c] LDS tiles

static __device__ __forceinline__ unsigned short f2b(float f) {
  union { float f; unsigned u; } v; v.f = f;
  return (unsigned short)((v.u + 0x7fffu + ((v.u >> 16) & 1u)) >> 16);
}
static __device__ __forceinline__ float b2f(unsigned short u) {
  union { unsigned u; float f; } v; v.u = ((unsigned)u) << 16;
  return v.f;
}
static __device__ __forceinline__ unsigned pk2(float a, float b) {
  return (unsigned)f2b(a) | ((unsigned)f2b(b) << 16);
}

// fmax with DPP-shifted self (identity 0 for invalid lanes: distances are >= 0)
#define DPPMAX(v, ctrl) \
  fmaxf((v), __int_as_float(__builtin_amdgcn_update_dpp(0, __float_as_int(v), (ctrl), 0xf, 0xf, false)))

// ---------------- weight folding: bn(conv(x)) = (W*s)x + (b*s+bb) ----------------
struct FoldArgs {
  const float *W, *b, *g, *bb;
  unsigned short* Wd;
  float* bd;
};
__global__ void fold4_bf16(FoldArgs a0, FoldArgs a1, FoldArgs a2, FoldArgs a3) {
  FoldArgs a = (blockIdx.y == 0) ? a0 : (blockIdx.y == 1) ? a1 : (blockIdx.y == 2) ? a2 : a3;
  int o = blockIdx.x;
  float sc = a.g[o] / sqrtf(1.0f + 1e-5f);
  for (int c = threadIdx.x; c < CCH; c += blockDim.x)
    a.Wd[o * CCH + c] = f2b(a.W[o * CCH + c] * sc);
  if (threadIdx.x == 0) a.bd[o] = a.b[o] * sc + a.bb[o];
}
__global__ void fold_w_f32(const float* __restrict__ W, const float* __restrict__ b,
                           const float* __restrict__ g, const float* __restrict__ bb,
                           float* __restrict__ Wd, float* __restrict__ bd, int Cin) {
  int o = blockIdx.x;
  float sc = g[o] / sqrtf(1.0f + 1e-5f);
  for (int c = threadIdx.x; c < Cin; c += blockDim.x)
    Wd[o * Cin + c] = W[o * Cin + c] * sc;
  if (threadIdx.x == 0) bd[o] = b[o] * sc + bb[o];
}

// ---------------- FPS v3: contiguous ownership, DPP value-reduce, slot broadcast ----
// thread tid owns points [tid*16, tid*16+16) => lane order == index order, so
// "first max" (numpy argmax) == lowest winning lane / lowest winning wave.
__global__ __launch_bounds__(512) void fps_kernel(const float* __restrict__ xyz,
                                                  int* __restrict__ cIdx) {
  #pragma clang fp contract(off)
  __shared__ float xs[NPTS], ys[NPTS], zs[NPTS];
  __shared__ uint2 slots[2][8];
  const int b = blockIdx.x, tid = threadIdx.x;
  const int lane = tid & 63, wid = tid >> 6;
  const float* xb = xyz + (size_t)b * NPTS * 3;

  float X[16], Y[16], Z[16], D[16];
  {
    const float4* src = (const float4*)xb + tid * 12;
    float tmp[48];
    #pragma unroll
    for (int q = 0; q < 12; ++q) {
      float4 t = src[q];
      tmp[q * 4 + 0] = t.x; tmp[q * 4 + 1] = t.y;
      tmp[q * 4 + 2] = t.z; tmp[q * 4 + 3] = t.w;
    }
    #pragma unroll
    for (int j = 0; j < 16; ++j) {
      X[j] = tmp[j * 3 + 0]; Y[j] = tmp[j * 3 + 1]; Z[j] = tmp[j * 3 + 2];
      D[j] = __builtin_inff();
      int p = tid * 16 + j;
      xs[p] = X[j]; ys[p] = Y[j]; zs[p] = Z[j];
    }
  }
  if (tid == 0) cIdx[b * SGRP] = 0;
  __syncthreads();
  float cx = xs[0], cy = ys[0], cz = zs[0];

  for (int step = 1; step < SGRP; ++step) {
    float bv = -1.0f; int bi = 0;
    #pragma unroll
    for (int j = 0; j < 16; ++j) {
      float dx = X[j] - cx, dy = Y[j] - cy, dz = Z[j] - cz;
      float d = (dx * dx + dy * dy) + dz * dz;   // contract off: numpy ulp-exact
      float nd = fminf(D[j], d);
      D[j] = nd;
      if (nd > bv) { bv = nd; bi = tid * 16 + j; }   // strict >: first max in-thread
    }
    // wave prefix-max (value only), pure VALU
    float m = bv;
    m = DPPMAX(m, 0x111);   // row_shr:1
    m = DPPMAX(m, 0x112);   // row_shr:2
    m = DPPMAX(m, 0x114);   // row_shr:4
    m = DPPMAX(m, 0x118);   // row_shr:8
    m = DPPMAX(m, 0x142);   // row_bcast:15
    m = DPPMAX(m, 0x143);   // row_bcast:31
    float wmax = __uint_as_float(__builtin_amdgcn_readlane(__float_as_uint(m), 63));
    unsigned long long msk = __ballot(bv == wmax);
    int srcLane = (int)__builtin_ctzll(msk);          // lowest lane == lowest index
    int wbi = __builtin_amdgcn_readlane(bi, srcLane);
    const int par = step & 1;
    if (lane == 0) slots[par][wid] = make_uint2(__float_as_uint(wmax), (unsigned)wbi);
    __syncthreads();
    float gbv = -1.0f; int gi = 0;
    #pragma unroll
    for (int w = 0; w < 8; ++w) {
      uint2 s = slots[par][w];
      float fv = __uint_as_float(s.x);
      if (fv > gbv) { gbv = fv; gi = (int)s.y; }      // strict >: lowest wave on tie
    }
    if (tid == 0) cIdx[b * SGRP + step] = gi;
    cx = xs[gi]; cy = ys[gi]; cz = zs[gi];            // LDS broadcast
  }
}

// ---------------- kNN v2: cached per-thread min, winner-only rescan, 1 barrier/iter ----
__global__ __launch_bounds__(256) void knn_kernel(const float* __restrict__ xyz,
                                                  const int* __restrict__ cIdx,
                                                  float* __restrict__ nbrDiff,
                                                  float* __restrict__ ctrW,
                                                  float* __restrict__ partials) {
  #pragma clang fp contract(off)
  __shared__ unsigned long long keyBuf[4];
  __shared__ int winners[KNBR];
  const int cid = blockIdx.x;
  const int b = cid >> 9;
  const int tid = threadIdx.x;
  const float* xb = xyz + (size_t)b * NPTS * 3;
  const int cI = cIdx[cid];
  const float cx = xb[cI * 3], cy = xb[cI * 3 + 1], cz = xb[cI * 3 + 2];
  const float cs = (cx * cx + cy * cy) + cz * cz;

  float d2[32];
  float mv = __builtin_inff(); int mi = 0;
  #pragma unroll
  for (int j = 0; j < 32; ++j) {
    int p = tid + (j << 8);
    float x = xb[p * 3], y = xb[p * 3 + 1], z = xb[p * 3 + 2];
    float ps = (x * x + y * y) + z * z;
    float dot = (cx * x + cy * y) + cz * z;
    d2[j] = (cs + ps) - 2.0f * dot;
    if (d2[j] < mv) { mv = d2[j]; mi = p; }   // strict <: lowest p on tie
  }
  if (tid < 4) keyBuf[tid] = 0xFFFFFFFFFFFFFFFFull;
  __syncthreads();

  for (int it = 0; it < KNBR; ++it) {
    if (tid == 0) keyBuf[(it + 2) & 3] = 0xFFFFFFFFFFFFFFFFull;
    float bv = mv; int bi = mi;
    #pragma unroll
    for (int s = 1; s < 64; s <<= 1) {
      float ov = __shfl_xor(bv, s); int oi = __shfl_xor(bi, s);
      if (ov < bv || (ov == bv && oi < bi)) { bv = ov; bi = oi; }
    }
    if ((tid & 63) == 0) {
      unsigned u = __float_as_uint(bv);
      unsigned m = u ^ (unsigned)(((int)u >> 31) | 0x80000000);   // monotone float->uint
      unsigned long long key = (((unsigned long long)m) << 32) | (unsigned long long)bi;
      atomicMin(&keyBuf[it & 3], key);
    }
    __syncthreads();
    unsigned long long k = keyBuf[it & 3];
    int wi = (int)(k & 0x1FFFu);
    if (tid == 0) winners[it] = wi;
    if (tid == (wi & 255)) {     // only the owner rescans its 32 values
      #pragma unroll
      for (int j = 0; j < 32; ++j)
        if (wi == tid + (j << 8)) d2[j] = __builtin_inff();
      mv = __builtin_inff(); mi = 0;
      #pragma unroll
      for (int j = 0; j < 32; ++j)
        if (d2[j] < mv) { mv = d2[j]; mi = tid + (j << 8); }
    }
  }
  __syncthreads();

  // gather diffs + per-center stats partials
  float sum = 0.f, sq = 0.f;
  if (tid < KNBR) {
    int w = winners[tid];
    float dx = xb[w * 3] - cx, dy = xb[w * 3 + 1] - cy, dz = xb[w * 3 + 2] - cz;
    size_t o = ((size_t)cid * KNBR + tid) * 3;
    nbrDiff[o + 0] = dx; nbrDiff[o + 1] = dy; nbrDiff[o + 2] = dz;
    sum = (dx + dy) + dz;
    sq = (dx * dx + dy * dy) + dz * dz;
  }
  if (tid < 64) {
    #pragma unroll
    for (int s = 1; s < 64; s <<= 1) { sum += __shfl_xor(sum, s); sq += __shfl_xor(sq, s); }
    if (tid == 0) { partials[cid * 2] = sum; partials[cid * 2 + 1] = sq; }
  }
  if (tid < 3) ctrW[(size_t)cid * 3 + tid] = xb[cI * 3 + tid];
}

// ---------------- per-batch std (ddof=1), deterministic fp64 tree ----------------
__global__ __launch_bounds__(256) void std_kernel(const float* __restrict__ partials,
                                                  float* __restrict__ stdv) {
  __shared__ double sd[256], sq[256];
  const int b = blockIdx.x, t = threadIdx.x;
  int i0 = (b * 512 + t) * 2;
  sd[t] = (double)partials[i0] + (double)partials[i0 + 512];
  sq[t] = (double)partials[i0 + 1] + (double)partials[i0 + 513];
  for (int st = 128; st > 0; st >>= 1) {
    __syncthreads();
    if (t < st) { sd[t] += sd[t + st]; sq[t] += sq[t + st]; }
  }
  if (t == 0) {
    double n = (double)(SGRP * KNBR * 3);
    double mean = sd[0] / n;
    double var = (sq[0] - sd[0] * mean) / (n - 1.0);
    stdv[b] = (float)sqrt(var);
  }
}

// ---------------- fused group MLP (t-net + pre res_block + maxpool) ----------------
// one block = 4 groups (128 l-columns), 8 waves, MFMA 16x16x32 bf16
static __device__ __forceinline__ void gemm_half(const unsigned short* __restrict__ W,
                                                 const unsigned short* ht,
                                                 int oBase, int n0, int r16, int g4,
                                                 f32x4 acc[3][4]) {
  for (int ks = 0; ks < 12; ++ks) {
    const int kOff = ks * 32 + g4 * 8;
    bf16x8 a[3], bb[4];
    #pragma unroll
    for (int i = 0; i < 3; ++i)
      a[i] = *(const bf16x8*)(W + (size_t)(oBase + i * 16 + r16) * CCH + kOff);
    #pragma unroll
    for (int j = 0; j < 4; ++j)
      bb[j] = *(const bf16x8*)(ht + (n0 + j * 16 + r16) * LDSP + kOff);
    #pragma unroll
    for (int i = 0; i < 3; ++i) {
      #pragma unroll
      for (int j = 0; j < 4; ++j)
        acc[i][j] = __builtin_amdgcn_mfma_f32_16x16x32_bf16(a[i], bb[j], acc[i][j], 0, 0, 0);
    }
  }
}

__global__ __launch_bounds__(512) void group_mlp_kernel(
    const float* __restrict__ alpha, const float* __restrict__ beta,
    const float* __restrict__ WtF, const float* __restrict__ btF,
    const unsigned short* __restrict__ W1, const float* __restrict__ b1,
    const unsigned short* __restrict__ W2, const float* __restrict__ b2,
    const float* __restrict__ nbrDiff, const float* __restrict__ ctrW,
    const float* __restrict__ stdv, unsigned short* __restrict__ feat) {
  __shared__ unsigned short ht[128 * LDSP];
  __shared__ float xtw[128 * 8];
  __shared__ float wtl[CCH * 6];
  __shared__ float btl[CCH];

  const int tid = threadIdx.x;
  const int lane = tid & 63, wid = tid >> 6;
  const int r16 = lane & 15, g4 = lane >> 4;
  const int bid = blockIdx.x;
  const int b = bid >> 7;
  const int sBase = (bid & 127) << 2;

  for (int i = tid; i < CCH * 6; i += 512) wtl[i] = WtF[i];
  for (int i = tid; i < CCH; i += 512) btl[i] = btF[i];

  const float inv = 1.0f / (stdv[b] + 1e-5f);
  if (tid < 128) {
    int g = tid >> 5, kk = tid & 31;
    int cid = b * SGRP + sBase + g;
    const float* nb = nbrDiff + ((size_t)cid * KNBR + kk) * 3;
    const float* cc = ctrW + (size_t)cid * 3;
    #pragma unroll
    for (int c = 0; c < 3; ++c) {
      xtw[tid * 8 + c] = alpha[c] * (nb[c] * inv) + beta[c];
      xtw[tid * 8 + 3 + c] = cc[c];
    }
  }
  __syncthreads();

  // conv1 (t-net, K=6) -> h0 bf16 into ht[l][o]
  {
    int l = tid & 127, oi = tid >> 7;
    float xv[6];
    #pragma unroll
    for (int c = 0; c < 6; ++c) xv[c] = xtw[l * 8 + c];
    for (int j = 0; j < 96; ++j) {
      int o = oi * 96 + j;
      float v = btl[o];
      #pragma unroll
      for (int c = 0; c < 6; ++c) v += wtl[o * 6 + c] * xv[c];
      ht[l * LDSP + o] = f2b(fmaxf(v, 0.0f));
    }
  }
  __syncthreads();

  const int oBase = wid * 48;

  // conv2: h1 = relu(W1 h0 + b1), overwrite ht by l-halves (disjoint rows)
  for (int half = 0; half < 2; ++half) {
    const int n0 = half * 64;
    f32x4 acc[3][4];
    #pragma unroll
    for (int i = 0; i < 3; ++i) {
      #pragma unroll
      for (int j = 0; j < 4; ++j) acc[i][j] = (f32x4){0.f, 0.f, 0.f, 0.f};
    }
    gemm_half(W1, ht, oBase, n0, r16, g4, acc);
    __syncthreads();   // all waves done reading this half's h0 rows
    #pragma unroll
    for (int i = 0; i < 3; ++i) {
      int o4 = oBase + i * 16 + g4 * 4;
      float bs0 = b1[o4], bs1 = b1[o4 + 1], bs2 = b1[o4 + 2], bs3 = b1[o4 + 3];
      #pragma unroll
      for (int j = 0; j < 4; ++j) {
        int row = n0 + j * 16 + r16;
        unsigned u0 = pk2(fmaxf(acc[i][j][0] + bs0, 0.f), fmaxf(acc[i][j][1] + bs1, 0.f));
        unsigned u1 = pk2(fmaxf(acc[i][j][2] + bs2, 0.f), fmaxf(acc[i][j][3] + bs3, 0.f));
        *(uint2*)(ht + row * LDSP + o4) = make_uint2(u0, u1);
      }
    }
    __syncthreads();
  }

  // conv3 + bias + residual(h0 recomputed) + relu + maxpool over K=32
  for (int half = 0; half < 2; ++half) {
    const int n0 = half * 64;
    f32x4 acc[3][4];
    #pragma unroll
    for (int i = 0; i < 3; ++i) {
      #pragma unroll
      for (int j = 0; j < 4; ++j) acc[i][j] = (f32x4){0.f, 0.f, 0.f, 0.f};
    }
    gemm_half(W2, ht, oBase, n0, r16, g4, acc);

    float bias2[3][4];
    #pragma unroll
    for (int i = 0; i < 3; ++i) {
      int o4 = oBase + i * 16 + g4 * 4;
      #pragma unroll
      for (int r = 0; r < 4; ++r) bias2[i][r] = b2[o4 + r];
    }
    float mx[3][2][4];
    #pragma unroll
    for (int i = 0; i < 3; ++i) {
      #pragma unroll
      for (int gg = 0; gg < 2; ++gg) {
        #pragma unroll
        for (int r = 0; r < 4; ++r) mx[i][gg][r] = 0.f;   // values are relu'd (>=0)
      }
    }
    #pragma unroll
    for (int j = 0; j < 4; ++j) {
      int l = n0 + j * 16 + r16;
      float xv[6];
      #pragma unroll
      for (int c = 0; c < 6; ++c) xv[c] = xtw[l * 8 + c];
      #pragma unroll
      for (int i = 0; i < 3; ++i) {
        int o4 = oBase + i * 16 + g4 * 4;
        #pragma unroll
        for (int r = 0; r < 4; ++r) {
          float h0 = btl[o4 + r];
          #pragma unroll
          for (int c = 0; c < 6; ++c) h0 += wtl[(o4 + r) * 6 + c] * xv[c];
          h0 = fmaxf(h0, 0.f);
          float v = fmaxf(acc[i][j][r] + bias2[i][r] + h0, 0.f);
          mx[i][j >> 1][r] = fmaxf(mx[i][j >> 1][r], v);
        }
      }
    }
    #pragma unroll
    for (int i = 0; i < 3; ++i) {
      #pragma unroll
      for (int gg = 0; gg < 2; ++gg) {
        float m0 = mx[i][gg][0], m1 = mx[i][gg][1], m2 = mx[i][gg][2], m3 = mx[i][gg][3];
        #pragma unroll
        for (int s = 1; s < 16; s <<= 1) {
          m0 = fmaxf(m0, __shfl_xor(m0, s));
          m1 = fmaxf(m1, __shfl_xor(m1, s));
          m2 = fmaxf(m2, __shfl_xor(m2, s));
          m3 = fmaxf(m3, __shfl_xor(m3, s));
        }
        if (r16 == 0) {
          int sIdx = sBase + half * 2 + gg;
          size_t fi = ((size_t)(b * SGRP + sIdx)) * CCH + oBase + i * 16 + g4 * 4;
          *(uint2*)(feat + fi) = make_uint2(pk2(m0, m1), pk2(m2, m3));
        }
      }
    }
  }
}

// ---------------- pos res_block on feat (B,384,512) + final transpose to (B,S,C) fp32 ----------------
__global__ __launch_bounds__(256) void pos_kernel(const unsigned short* __restrict__ feat,
                                                  const unsigned short* __restrict__ Wp1,
                                                  const float* __restrict__ bp1,
                                                  const unsigned short* __restrict__ Wp2,
                                                  const float* __restrict__ bp2,
                                                  float* __restrict__ out) {
  __shared__ unsigned short h1[16 * LDSP];
  const int tid = threadIdx.x;
  const int lane = tid & 63, wid = tid >> 6;
  const int r16 = lane & 15, g4 = lane >> 4;
  const int bid = blockIdx.x;
  const int b = bid >> 5;
  const int s0 = (bid & 31) << 4;
  const size_t rowBase = ((size_t)(b * SGRP + s0 + r16)) * CCH;

  f32x4 acc[6];
  #pragma unroll
  for (int i = 0; i < 6; ++i) acc[i] = (f32x4){0.f, 0.f, 0.f, 0.f};
  for (int ks = 0; ks < 12; ++ks) {
    const int kOff = ks * 32 + g4 * 8;
    bf16x8 bfr = *(const bf16x8*)(feat + rowBase + kOff);
    #pragma unroll
    for (int i = 0; i < 6; ++i) {
      bf16x8 a = *(const bf16x8*)(Wp1 + (size_t)(wid * 96 + i * 16 + r16) * CCH + kOff);
      acc[i] = __builtin_amdgcn_mfma_f32_16x16x32_bf16(a, bfr, acc[i], 0, 0, 0);
    }
  }
  #pragma unroll
  for (int i = 0; i < 6; ++i) {
    int o4 = wid * 96 + i * 16 + g4 * 4;
    unsigned u0 = pk2(fmaxf(acc[i][0] + bp1[o4 + 0], 0.f), fmaxf(acc[i][1] + bp1[o4 + 1], 0.f));
    unsigned u1 = pk2(fmaxf(acc[i][2] + bp1[o4 + 2], 0.f), fmaxf(acc[i][3] + bp1[o4 + 3], 0.f));
    *(uint2*)(h1 + r16 * LDSP + o4) = make_uint2(u0, u1);
  }
  __syncthreads();

  f32x4 acc2[6];
  #pragma unroll
  for (int i = 0; i < 6; ++i) acc2[i] = (f32x4){0.f, 0.f, 0.f, 0.f};
  for (int ks = 0; ks < 12; ++ks) {
    const int kOff = ks * 32 + g4 * 8;
    bf16x8 bfr = *(const bf16x8*)(h1 + r16 * LDSP + kOff);
    #pragma unroll
    for (int i = 0; i < 6; ++i) {
      bf16x8 a = *(const bf16x8*)(Wp2 + (size_t)(wid * 96 + i * 16 + r16) * CCH + kOff);
      acc2[i] = __builtin_amdgcn_mfma_f32_16x16x32_bf16(a, bfr, acc2[i], 0, 0, 0);
    }
  }
  #pragma unroll
  for (int i = 0; i < 6; ++i) {
    int o4 = wid * 96 + i * 16 + g4 * 4;
    uint2 rr = *(const uint2*)(feat + rowBase + o4);
    float4 v;
    v.x = fmaxf(acc2[i][0] + bp2[o4 + 0] + b2f((unsigned short)(rr.x & 0xffff)), 0.f);
    v.y = fmaxf(acc2[i][1] + bp2[o4 + 1] + b2f((unsigned short)(rr.x >> 16)), 0.f);
    v.z = fmaxf(acc2[i][2] + bp2[o4 + 2] + b2f((unsigned short)(rr.y & 0xffff)), 0.f);
    v.w = fmaxf(acc2[i][3] + bp2[o4 + 3] + b2f((unsigned short)(rr.y >> 16)), 0.f);
    *(float4*)(out + rowBase + o4) = v;
  }
}

// ---------------- launch ----------------
extern "C" void kernel_launch(void* const* d_in, const int* in_sizes, int n_in,
                              void* d_out, int out_size, void* d_ws, size_t ws_size,
                              hipStream_t stream) {
  (void)in_sizes; (void)n_in; (void)out_size; (void)ws_size;
  const float* xyz   = (const float*)d_in[0];
  const float* alpha = (const float*)d_in[1];
  const float* beta  = (const float*)d_in[2];
  const float* Wt    = (const float*)d_in[3];
  const float* bt    = (const float*)d_in[4];
  const float* gt    = (const float*)d_in[5];
  const float* bbt   = (const float*)d_in[6];
  const float* Wpre1 = (const float*)d_in[7];
  const float* bpre1 = (const float*)d_in[8];
  const float* gpre1 = (const float*)d_in[9];
  const float* bbpre1= (const float*)d_in[10];
  const float* Wpre2 = (const float*)d_in[11];
  const float* bpre2 = (const float*)d_in[12];
  const float* gpre2 = (const float*)d_in[13];
  const float* bbpre2= (const float*)d_in[14];
  const float* Wpos1 = (const float*)d_in[15];
  const float* bpos1 = (const float*)d_in[16];
  const float* gpos1 = (const float*)d_in[17];
  const float* bbpos1= (const float*)d_in[18];
  const float* Wpos2 = (const float*)d_in[19];
  const float* bpos2 = (const float*)d_in[20];
  const float* gpos2 = (const float*)d_in[21];
  const float* bbpos2= (const float*)d_in[22];

  char* ws = (char*)d_ws;
  size_t off = 0;
  auto alloc = [&](size_t bytes) -> void* {
    void* p = ws + off;
    off += (bytes + 255) & ~(size_t)255;
    return p;
  };
  float* WtF = (float*)alloc(CCH * 6 * 4);
  float* btF = (float*)alloc(CCH * 4);
  unsigned short* W1 = (unsigned short*)alloc(CCH * CCH * 2);
  float* b1 = (float*)alloc(CCH * 4);
  unsigned short* W2 = (unsigned short*)alloc(CCH * CCH * 2);
  float* b2 = (float*)alloc(CCH * 4);
  unsigned short* Wp1 = (unsigned short*)alloc(CCH * CCH * 2);
  float* bp1 = (float*)alloc(CCH * 4);
  unsigned short* Wp2 = (unsigned short*)alloc(CCH * CCH * 2);
  float* bp2 = (float*)alloc(CCH * 4);
  int* cIdx = (int*)alloc(8 * SGRP * 4);
  float* ctrW = (float*)alloc(8 * SGRP * 3 * 4);
  float* nbrD = (float*)alloc((size_t)8 * SGRP * KNBR * 3 * 4);
  float* partials = (float*)alloc(8 * SGRP * 2 * 4);
  float* stdv = (float*)alloc(8 * 4);
  unsigned short* feat = (unsigned short*)alloc((size_t)8 * SGRP * CCH * 2);

  fold_w_f32<<<CCH, 64, 0, stream>>>(Wt, bt, gt, bbt, WtF, btF, 6);
  FoldArgs fa0{Wpre1, bpre1, gpre1, bbpre1, W1, b1};
  FoldArgs fa1{Wpre2, bpre2, gpre2, bbpre2, W2, b2};
  FoldArgs fa2{Wpos1, bpos1, gpos1, bbpos1, Wp1, bp1};
  FoldArgs fa3{Wpos2, bpos2, gpos2, bbpos2, Wp2, bp2};
  fold4_bf16<<<dim3(CCH, 4), 128, 0, stream>>>(fa0, fa1, fa2, fa3);

  fps_kernel<<<8, 512, 0, stream>>>(xyz, cIdx);
  knn_kernel<<<8 * SGRP, 256, 0, stream>>>(xyz, cIdx, nbrD, ctrW, partials);
  std_kernel<<<8, 256, 0, stream>>>(partials, stdv);
  group_mlp_kernel<<<1024, 512, 0, stream>>>(alpha, beta, WtF, btF, W1, b1, W2, b2,
                                             nbrD, ctrW, stdv, feat);
  pos_kernel<<<256, 256, 0, stream>>>(feat, Wp1, bp1, Wp2, bp2, (float*)d_out);
}